// Round 5
// baseline (1049.411 us; speedup 1.0000x reference)
//
#include <hip/hip_runtime.h>

#define NSEG 128
#define BB 2
#define CC 768
#define CC4 (CC/4)          // 192 channel quads
#define HP 28
#define WP 28
#define HI 392
#define WI 392
#define NPIX (HI*WI)        // 153664
#define NPIX4 (NPIX/4)      // 38416
#define NXBLK 8
#define XSPAN (NPIX4/NXBLK) // 4802 float4-groups per block (exact: 8*4802=38416)

typedef float f32x4 __attribute__((ext_vector_type(4)));   // native vector for nontemporal store

// Pack clamped segment ids to uint8, 4 pixels/thread.
__global__ void pid_kernel(const int* __restrict__ mask, unsigned int* __restrict__ sb) {
    int g = blockIdx.x * blockDim.x + threadIdx.x;
    if (g >= BB * NPIX4) return;
    int4 m = ((const int4*)mask)[g];
    unsigned int s0 = (unsigned int)min(max(m.x, 0), NSEG - 1);
    unsigned int s1 = (unsigned int)min(max(m.y, 0), NSEG - 1);
    unsigned int s2 = (unsigned int)min(max(m.z, 0), NSEG - 1);
    unsigned int s3 = (unsigned int)min(max(m.w, 0), NSEG - 1);
    sb[g] = s0 | (s1 << 8) | (s2 << 16) | (s3 << 24);
}

// One block per patch cell; accumulate feature vector into transposed sums[b][c][s].
__global__ void accum_kernel(const float* __restrict__ F, const int* __restrict__ mask,
                             float* __restrict__ sums, float* __restrict__ counts) {
    int cell = blockIdx.x;                   // 0 .. BB*HP*WP-1
    int b = cell / (HP * WP);
    int rem = cell - b * (HP * WP);
    int hp = rem / WP;
    int wp = rem - hp * WP;
    // ih = hp*HI/HP = hp*14 exactly; iw = wp*14
    int m = mask[(size_t)b * NPIX + (hp * 14) * WI + (wp * 14)];
    int s = min(max(m, 0), NSEG - 1);
    for (int c = threadIdx.x; c < CC; c += blockDim.x) {
        float v = F[((b * CC + c) * HP + hp) * WP + wp];
        atomicAdd(&sums[(size_t)(b * CC + c) * NSEG + s], v);
    }
    if (threadIdx.x == 0) atomicAdd(&counts[b * NSEG + s], 1.0f);
}

// In-place: convert channel-quad (4c4..4c4+3) sums into interleaved float4
// averages occupying the SAME 2 KB region. One block per (b, c4); read all four
// channels into registers, sync, write back interleaved. No extra workspace.
__global__ __launch_bounds__(128) void div_kernel(float* __restrict__ sums,
                                                  const float* __restrict__ counts) {
    int quad = blockIdx.x;                   // 0 .. BB*CC4-1
    int b = quad / CC4;
    int s = threadIdx.x;                     // 0..127
    float* base = sums + ((size_t)quad << 9);        // quad*4*NSEG floats (2 KB)
    float cnt = counts[b * NSEG + s];
    float v0 = base[s];
    float v1 = base[s + NSEG];
    float v2 = base[s + 2 * NSEG];
    float v3 = base[s + 3 * NSEG];
    float inv = (cnt > 0.0f) ? (1.0f / cnt) : 0.0f;
    __syncthreads();
    ((f32x4*)base)[s] = (f32x4){v0 * inv, v1 * inv, v2 * inv, v3 * inv};
}

// Paint v3: 4 channels (one quad) per block; each block owns a 4802-group x-span,
// so it emits only 4 long contiguous write streams (76.8 KB each) — good DRAM page
// locality. The 2 KB quad table lives in LDS, so the VMEM queue carries ONLY the
// coalesced sb reads and the nontemporal output stores; divergent gathers ride the
// LDS pipe (lgkmcnt) where their cost (~8-16 cyc/wave-instr) hides under the stores.
__global__ __launch_bounds__(256) void paint_kernel(const f32x4* __restrict__ avg4,
                                                    const unsigned int* __restrict__ sb,
                                                    float* __restrict__ out) {
    __shared__ f32x4 tbl[NSEG];              // 2 KB
    int q = blockIdx.y;                      // channel quad
    int b = blockIdx.z;
    if (threadIdx.x < NSEG)
        tbl[threadIdx.x] = avg4[(((size_t)(b * CC4 + q)) << 7) + threadIdx.x];
    __syncthreads();

    const unsigned int* sbp = sb + (size_t)b * NPIX4;
    f32x4* outp = (f32x4*)out + (size_t)(b * CC + 4 * q) * NPIX4;
    int gend = (blockIdx.x + 1) * XSPAN;
    for (int g = blockIdx.x * XSPAN + threadIdx.x; g < gend; g += 256) {
        unsigned int packed = sbp[g];
        f32x4 a = tbl[packed & 255];
        f32x4 bb = tbl[(packed >> 8) & 255];
        f32x4 c = tbl[(packed >> 16) & 255];
        f32x4 d = tbl[(packed >> 24) & 255];
        #pragma unroll
        for (int j = 0; j < 4; ++j) {
            f32x4 v = {a[j], bb[j], c[j], d[j]};
            __builtin_nontemporal_store(v, outp + (size_t)j * NPIX4 + g);
        }
    }
}

extern "C" void kernel_launch(void* const* d_in, const int* in_sizes, int n_in,
                              void* d_out, int out_size, void* d_ws, size_t ws_size,
                              hipStream_t stream) {
    const float* F = (const float*)d_in[0];
    const int* mask = (const int*)d_in[1];
    float* out = (float*)d_out;

    float* sums = (float*)d_ws;                            // BB*CC*NSEG floats (786,432 B)
    float* counts = sums + BB * CC * NSEG;                 // BB*NSEG floats (1,024 B)
    unsigned int* sb = (unsigned int*)(counts + BB * NSEG);// BB*NPIX4 words (307,328 B)
    // Total workspace: 1,094,784 B — identical footprint to the verified baseline.

    // Zero sums + counts (ws is poisoned each call).
    (void)hipMemsetAsync(d_ws, 0, (size_t)(BB * CC * NSEG + BB * NSEG) * sizeof(float), stream);

    int ngroups = BB * NPIX4;                                   // 76,832
    pid_kernel<<<(ngroups + 255) / 256, 256, 0, stream>>>(mask, sb);
    accum_kernel<<<BB * HP * WP, 256, 0, stream>>>(F, mask, sums, counts);
    div_kernel<<<BB * CC4, 128, 0, stream>>>(sums, counts);
    paint_kernel<<<dim3(NXBLK, CC4, BB), 256, 0, stream>>>(
        (const f32x4*)sums, sb, out);
}

// Round 6
// 1005.731 us; speedup vs baseline: 1.0434x; 1.0434x over previous
//
#include <hip/hip_runtime.h>

#define NSEG 128
#define BB 2
#define CC 768
#define HP 28
#define WP 28
#define HI 392
#define WI 392
#define NPIX (HI*WI)        // 153664
#define NPIX4 (NPIX/4)      // 38416
#define NSPLIT 4
#define SPAN (NPIX4/NSPLIT) // 9604 float4-groups per block (exact: 4*9604=38416)

typedef float f32x4 __attribute__((ext_vector_type(4)));   // native vector for nontemporal store

// Pack clamped segment ids to uint8, 4 pixels/thread.
__global__ void pid_kernel(const int* __restrict__ mask, unsigned int* __restrict__ sb) {
    int g = blockIdx.x * blockDim.x + threadIdx.x;
    if (g >= BB * NPIX4) return;
    int4 m = ((const int4*)mask)[g];
    unsigned int s0 = (unsigned int)min(max(m.x, 0), NSEG - 1);
    unsigned int s1 = (unsigned int)min(max(m.y, 0), NSEG - 1);
    unsigned int s2 = (unsigned int)min(max(m.z, 0), NSEG - 1);
    unsigned int s3 = (unsigned int)min(max(m.w, 0), NSEG - 1);
    sb[g] = s0 | (s1 << 8) | (s2 << 16) | (s3 << 24);
}

// One block per patch cell; accumulate feature vector into transposed sums[b][c][s].
__global__ void accum_kernel(const float* __restrict__ F, const int* __restrict__ mask,
                             float* __restrict__ sums, float* __restrict__ counts) {
    int cell = blockIdx.x;                   // 0 .. BB*HP*WP-1
    int b = cell / (HP * WP);
    int rem = cell - b * (HP * WP);
    int hp = rem / WP;
    int wp = rem - hp * WP;
    // ih = hp*HI/HP = hp*14 exactly; iw = wp*14
    int m = mask[(size_t)b * NPIX + (hp * 14) * WI + (wp * 14)];
    int s = min(max(m, 0), NSEG - 1);
    for (int c = threadIdx.x; c < CC; c += blockDim.x) {
        float v = F[((b * CC + c) * HP + hp) * WP + wp];
        atomicAdd(&sums[(size_t)(b * CC + c) * NSEG + s], v);
    }
    if (threadIdx.x == 0) atomicAdd(&counts[b * NSEG + s], 1.0f);
}

// In-place divide: avg[b][c][s] = count>0 ? sum/count : 0  (plain [b][c][s] layout)
__global__ void div_kernel(float* __restrict__ sums, const float* __restrict__ counts) {
    int i = blockIdx.x * blockDim.x + threadIdx.x;   // < BB*CC*NSEG
    int b = i / (CC * NSEG);
    int s = i & (NSEG - 1);
    float cnt = counts[b * NSEG + s];
    float v = sums[i];
    sums[i] = (cnt > 0.0f) ? (v / cnt) : 0.0f;
}

// Paint v4: ONE channel per block (grid = NSPLIT x CC x BB). Each block writes a
// single contiguous 153 KB stream of nontemporal float4 stores — the same long
// linear-stream pattern as the runtime's 6.2 TB/s fill kernel. The 512 B channel
// table sits in LDS; scalar ds_read_b32 gathers (entry s -> bank s%32, ~2
// lanes/bank for random ids = conflict-free per m136) keep the VMEM queue free
// for sb reads + stores only. sb (307 KB) is re-read per channel but stays
// L2-resident because output stores are nontemporal.
__global__ __launch_bounds__(256) void paint_kernel(const float* __restrict__ avg,
                                                    const unsigned int* __restrict__ sb,
                                                    float* __restrict__ out) {
    __shared__ float tbl[NSEG];              // 512 B
    int c = blockIdx.y;
    int b = blockIdx.z;
    if (threadIdx.x < NSEG)
        tbl[threadIdx.x] = avg[(((size_t)(b * CC + c)) << 7) + threadIdx.x];
    __syncthreads();

    const unsigned int* sbp = sb + (size_t)b * NPIX4;
    f32x4* outp = (f32x4*)out + (size_t)(b * CC + c) * NPIX4;
    int gend = (blockIdx.x + 1) * SPAN;
    #pragma unroll 4
    for (int g = blockIdx.x * SPAN + threadIdx.x; g < gend; g += 256) {
        unsigned int p = sbp[g];
        f32x4 v = {tbl[p & 255], tbl[(p >> 8) & 255],
                   tbl[(p >> 16) & 255], tbl[(p >> 24) & 255]};
        __builtin_nontemporal_store(v, outp + g);
    }
}

extern "C" void kernel_launch(void* const* d_in, const int* in_sizes, int n_in,
                              void* d_out, int out_size, void* d_ws, size_t ws_size,
                              hipStream_t stream) {
    const float* F = (const float*)d_in[0];
    const int* mask = (const int*)d_in[1];
    float* out = (float*)d_out;

    float* sums = (float*)d_ws;                            // BB*CC*NSEG floats (786,432 B)
    float* counts = sums + BB * CC * NSEG;                 // BB*NSEG floats (1,024 B)
    unsigned int* sb = (unsigned int*)(counts + BB * NSEG);// BB*NPIX4 words (307,328 B)
    // Total workspace: 1,094,784 B — identical footprint to the verified baseline.

    // Zero sums + counts (ws is poisoned each call).
    (void)hipMemsetAsync(d_ws, 0, (size_t)(BB * CC * NSEG + BB * NSEG) * sizeof(float), stream);

    int ngroups = BB * NPIX4;                                   // 76,832
    pid_kernel<<<(ngroups + 255) / 256, 256, 0, stream>>>(mask, sb);
    accum_kernel<<<BB * HP * WP, 256, 0, stream>>>(F, mask, sums, counts);
    div_kernel<<<(BB * CC * NSEG) / 256, 256, 0, stream>>>(sums, counts);
    paint_kernel<<<dim3(NSPLIT, CC, BB), 256, 0, stream>>>(sums, sb, out);
}